// Round 9
// baseline (244.841 us; speedup 1.0000x reference)
//
#include <hip/hip_runtime.h>
#include <cmath>

#define D_IN 256
#define H_DIM 128
#define NUM_GRAPHS 1024
#define CHUNK 64
#define KCH 4          // chunks per persistent block
#define MAXSEG 4
#define REC_F 768      // floats per record: ewsum[256], ssum[256], mx[256]

typedef __attribute__((ext_vector_type(8))) __bf16 bf16x8;
typedef __attribute__((ext_vector_type(4))) float f32x4;
typedef __attribute__((ext_vector_type(4))) unsigned short ushort4v;

__device__ inline float b2f(unsigned short u) {
    unsigned int v = ((unsigned int)u) << 16;
    return __builtin_bit_cast(float, v);
}

// lgkm-only barrier: does NOT drain vmcnt, so prefetch loads stay in flight.
__device__ inline void bar_lds() {
    asm volatile("s_waitcnt lgkmcnt(0)" ::: "memory");
    __builtin_amdgcn_s_barrier();
    asm volatile("" ::: "memory");
}

// ---------------------------------------------------------------------------
// Pack W1 (f32 [256][128]) into bf16 MFMA B-fragment order.
// B-frag for mfma_f32_16x16x32_bf16: lane l holds B[k][n], n = nt*16 + (l&15),
// k = ks*32 + (l>>4)*8 + i. packed[((nt*8+ks)*64 + l)*8 + i]
// ---------------------------------------------------------------------------
__global__ void pack_w1(const float* __restrict__ W1, ushort* __restrict__ packed) {
    int tid = blockIdx.x * 256 + threadIdx.x;
    if (tid >= 8 * 8 * 64) return;
    int nt = tid >> 9;
    int ks = (tid >> 6) & 7;
    int l = tid & 63;
    int col = nt * 16 + (l & 15);
    int kbase = ks * 32 + ((l >> 4) & 3) * 8;
#pragma unroll
    for (int i = 0; i < 8; ++i) {
        float v = W1[(size_t)(kbase + i) * H_DIM + col];
        __bf16 b = (__bf16)v;
        packed[(size_t)tid * 8 + i] = __builtin_bit_cast(unsigned short, b);
    }
}

// ---------------------------------------------------------------------------
// Persistent fused kernel: each block owns KCH consecutive 64-row chunks.
// nt-split: wave w computes ALL 64 rows over H-cols [w*32,+32), W1 in regs
// (loaded once per block). Chunk c+1's x loads issued during chunk c compute;
// lgkm-only barriers keep them in flight. 2 barriers per chunk.
// ---------------------------------------------------------------------------
__global__ __launch_bounds__(256) void fused_kernel(
    const float* __restrict__ x, const ushort* __restrict__ w1p,
    const float* __restrict__ b1, const float* __restrict__ W2,
    const float* __restrict__ b2, const int* __restrict__ batch,
    float* __restrict__ recs, int2* __restrict__ hdr,
    float* __restrict__ zpart, int N, int NB) {
    int tid = threadIdx.x;
    int l = tid & 63;
    int w = tid >> 6;
    int r16 = l & 15;
    int kg = l >> 4;
    int c0 = blockIdx.x * KCH;
    if (c0 >= NB) {
        if (tid == 0) zpart[blockIdx.x] = 0.f;
        return;
    }
    int c1 = min(c0 + KCH, NB);

    __shared__ ushort sx[CHUNK * D_IN];   // 32 KB bf16 tile, XOR-swizzled
    __shared__ float pscore[CHUNK][4];    // [row][wave] partial scores
    __shared__ int sbatch[CHUNK];         // wave0-private scratch
    __shared__ int seglist[2][MAXSEG + 1];  // double-buffered by chunk parity
    __shared__ int seggid[2][MAXSEG];
    __shared__ int snseg[2];

    // ---- per-block prologue: W1 slice -> registers (once) ----
    bf16x8 breg0[8], breg1[8];
#pragma unroll
    for (int ks = 0; ks < 8; ++ks) {
        breg0[ks] = *(const bf16x8*)(w1p + ((size_t)((w * 2) * 8 + ks) * 64 + l) * 8);
        breg1[ks] = *(const bf16x8*)(w1p + ((size_t)((w * 2 + 1) * 8 + ks) * 64 + l) * 8);
    }
    float w2v[2], b1v[2];
#pragma unroll
    for (int q = 0; q < 2; ++q) {
        int c = (w * 2 + q) * 16 + r16;
        w2v[q] = W2[c];
        b1v[q] = b1[c];
    }
    float bb = b2[0];

    int srow = tid >> 2;   // staging row this thread owns
    int sgb = tid & 3;     // staging granule base

    // ---- prefetch chunk c0 (x rows + batch) ----
    f32x4 xv[16];
    int bval = -1;
    {
        long long base = (long long)c0 * CHUNK;
        long long grow = base + srow;
        if (grow >= N) grow = N - 1;
        const float* xr = x + grow * D_IN;
#pragma unroll
        for (int j = 0; j < 8; ++j) {
            int g = sgb + 4 * j;
            xv[2 * j] = *(const f32x4*)(xr + g * 8);
            xv[2 * j + 1] = *(const f32x4*)(xr + g * 8 + 4);
        }
        if (w == 0) {
            long long bi = base + l;
            bval = (bi < N) ? batch[bi] : -1;
        }
    }

    float zloc = 0.f;

    for (int c = c0; c < c1; ++c) {
        int pb = c & 1;
        long long base = (long long)c * CHUNK;
        int chunkN = (int)min((long long)CHUNK, (long long)N - base);

        // ---- STAGE: cvt xv -> sx (waits on xv loads) ----
        {
            unsigned rowswz = (unsigned)(srow & 7) << 4;
#pragma unroll
            for (int j = 0; j < 8; ++j) {
                int g = sgb + 4 * j;
                bf16x8 pk;
#pragma unroll
                for (int i = 0; i < 4; ++i) {
                    pk[i] = (__bf16)xv[2 * j][i];
                    pk[i + 4] = (__bf16)xv[2 * j + 1][i];
                }
                unsigned addr = ((unsigned)(srow * 512 + g * 16)) ^ rowswz;
                *(bf16x8*)((char*)sx + addr) = pk;
            }
        }

        // ---- wave0: segment scan into parity buffer ----
        if (w == 0) {
            sbatch[l] = bval;
            int prev = __shfl_up(bval, 1, 64);
            bool flag = (l < chunkN) && (l == 0 || bval != prev);
            unsigned long long m = __ballot(flag);
            if (l == 0) {
                int ns = 0;
                while (m && ns < MAXSEG) {
                    int b = __ffsll(m) - 1;
                    seglist[pb][ns] = b;
                    seggid[pb][ns] = sbatch[b];
                    ns++;
                    m &= m - 1;
                }
                snseg[pb] = ns;
                seglist[pb][ns] = chunkN;
            }
        }

        // ---- issue prefetch for chunk c+1 (xv regs now dead) ----
        if (c + 1 < c1) {
            long long nbase = (long long)(c + 1) * CHUNK;
            long long grow = nbase + srow;
            if (grow >= N) grow = N - 1;
            const float* xr = x + grow * D_IN;
#pragma unroll
            for (int j = 0; j < 8; ++j) {
                int g = sgb + 4 * j;
                xv[2 * j] = *(const f32x4*)(xr + g * 8);
                xv[2 * j + 1] = *(const f32x4*)(xr + g * 8 + 4);
            }
            if (w == 0) {
                long long bi = nbase + l;
                bval = (bi < N) ? batch[bi] : -1;
            }
        }

        bar_lds();  // barrier A: sx + seglist ready (vm loads stay in flight)

        // ---- MFMA: acc[mt][q] over 4 row-tiles x this wave's 2 n-tiles ----
        f32x4 acc[4][2] = {};
#pragma unroll
        for (int ks = 0; ks < 8; ++ks) {
#pragma unroll
            for (int mt = 0; mt < 4; ++mt) {
                int row = mt * 16 + r16;
                unsigned addr = ((unsigned)(row * 512 + ks * 64 + kg * 16)) ^
                                ((unsigned)(row & 7) << 4);
                bf16x8 af = *(const bf16x8*)((const char*)sx + addr);
                acc[mt][0] = __builtin_amdgcn_mfma_f32_16x16x32_bf16(af, breg0[ks], acc[mt][0], 0, 0, 0);
                acc[mt][1] = __builtin_amdgcn_mfma_f32_16x16x32_bf16(af, breg1[ks], acc[mt][1], 0, 0, 0);
            }
        }
        // partial-score epilogue over this wave's 32 cols
#pragma unroll
        for (int mt = 0; mt < 4; ++mt) {
#pragma unroll
            for (int reg = 0; reg < 4; ++reg) {
                float p = fmaxf(acc[mt][0][reg] + b1v[0], 0.f) * w2v[0] +
                          fmaxf(acc[mt][1][reg] + b1v[1], 0.f) * w2v[1];
                p += __shfl_xor(p, 1, 64);
                p += __shfl_xor(p, 2, 64);
                p += __shfl_xor(p, 4, 64);
                p += __shfl_xor(p, 8, 64);
                if (r16 == 0) pscore[mt * 16 + kg * 4 + reg][w] = p;
            }
        }

        bar_lds();  // barrier B: pscore complete

        f32x4 ps = *(const f32x4*)&pscore[l][0];
        float e_l = (l < chunkN) ? __expf(ps[0] + ps[1] + ps[2] + ps[3] + bb) : 0.f;

        if (w == 0) {
            float z = e_l;
            z += __shfl_xor(z, 1, 64);
            z += __shfl_xor(z, 2, 64);
            z += __shfl_xor(z, 4, 64);
            z += __shfl_xor(z, 8, 64);
            z += __shfl_xor(z, 16, 64);
            z += __shfl_xor(z, 32, 64);
            if (l == 0) zloc += z;
        }

        int nseg = snseg[pb];

        // ---- POOL: wave w pools its own rows [w*16,+16); per-wave flush ----
        f32x4 asum = {0.f, 0.f, 0.f, 0.f};
        f32x4 ssum = {0.f, 0.f, 0.f, 0.f};
        f32x4 mx = {-INFINITY, -INFINITY, -INFINITY, -INFINITY};

        for (int sg = 0; sg < nseg; ++sg) {
            int sStart = seglist[pb][sg];
            int sEnd = seglist[pb][sg + 1];
#pragma unroll
            for (int j = 0; j < 16; ++j) {
                int row = w * 16 + j;
                float wj = __shfl(e_l, row, 64);
                bool in = (row >= sStart) && (row < sEnd);
                unsigned addr = ((unsigned)(row * 512 + l * 8)) ^
                                ((unsigned)(row & 7) << 4);
                ushort4v hv = *(const ushort4v*)((const char*)sx + addr);
                float wje = in ? wj : 0.f;
#pragma unroll
                for (int cc = 0; cc < 4; ++cc) {
                    float v = b2f(hv[cc]);
                    asum[cc] += v * wje;
                    ssum[cc] += in ? v : 0.f;
                    mx[cc] = fmaxf(mx[cc], in ? v : -INFINITY);
                }
            }
            float* rb = recs + ((size_t)(c * MAXSEG + sg) * 4 + w) * REC_F;
            *(f32x4*)(rb + l * 4) = asum;
            *(f32x4*)(rb + 256 + l * 4) = ssum;
            *(f32x4*)(rb + 512 + l * 4) = mx;
            if (w == 0 && l == 0)
                hdr[c * MAXSEG + sg] = make_int2(seggid[pb][sg], sEnd - sStart);
#pragma unroll
            for (int cc = 0; cc < 4; ++cc) {
                asum[cc] = 0.f;
                ssum[cc] = 0.f;
                mx[cc] = -INFINITY;
            }
        }
        if (w == 0 && l == 0) {
            for (int sg = nseg; sg < MAXSEG; ++sg)
                hdr[c * MAXSEG + sg] = make_int2(-1, 0);
        }
    }

    if (w == 0 && l == 0) zpart[blockIdx.x] = zloc;
}

// ---------------------------------------------------------------------------
__global__ __launch_bounds__(256) void zreduce_kernel(
    const float* __restrict__ zpart, int n, float* __restrict__ MZ) {
    int tid = threadIdx.x;
    float z = 0.f;
    for (int i = tid; i < n; i += 256) z += zpart[i];
    __shared__ float sz[256];
    sz[tid] = z;
    __syncthreads();
    for (int off = 128; off > 0; off >>= 1) {
        if (tid < off) sz[tid] += sz[tid + off];
        __syncthreads();
    }
    if (tid == 0) MZ[0] = 1.f / sz[0];
}

// ---------------------------------------------------------------------------
__device__ inline int lower_bound_i(const int* __restrict__ arr, int n, int val) {
    int lo = 0, hi = n;
    while (lo < hi) {
        int mid = (lo + hi) >> 1;
        if (arr[mid] < val) lo = mid + 1; else hi = mid;
    }
    return lo;
}

// One block per graph; wave w consumes the wave-w quarter of each record.
__global__ __launch_bounds__(256) void combine_kernel(
    const float* __restrict__ recs, const int2* __restrict__ hdr,
    const float* __restrict__ MZ,
    const int* __restrict__ batch, int N, float* __restrict__ out) {
    int g = blockIdx.x;
    int tid = threadIdx.x;
    int w = tid >> 6;
    int l = tid & 63;
    float invZ = MZ[0];

    __shared__ int sb[2];
    if (tid < 2) sb[tid] = lower_bound_i(batch, N, g + tid);
    __syncthreads();
    int start = sb[0], end = sb[1];

    f32x4 ew = {0.f, 0.f, 0.f, 0.f};
    f32x4 ss = {0.f, 0.f, 0.f, 0.f};
    f32x4 mxv = {-INFINITY, -INFINITY, -INFINITY, -INFINITY};
    int cnt = 0;
    if (end > start) {
        int b0 = start >> 6, b1 = (end - 1) >> 6;
        for (int b = b0; b <= b1; ++b) {
#pragma unroll
            for (int sg = 0; sg < MAXSEG; ++sg) {
                int2 h = hdr[b * MAXSEG + sg];
                if (h.x == g) {
                    const float* rb = recs + ((size_t)(b * MAXSEG + sg) * 4 + w) * REC_F;
                    f32x4 a = *(const f32x4*)(rb + l * 4);
                    f32x4 s = *(const f32x4*)(rb + 256 + l * 4);
                    f32x4 m = *(const f32x4*)(rb + 512 + l * 4);
#pragma unroll
                    for (int c = 0; c < 4; ++c) {
                        ew[c] += a[c];
                        ss[c] += s[c];
                        mxv[c] = fmaxf(mxv[c], m[c]);
                    }
                    cnt += h.y;
                }
            }
        }
    }

    __shared__ float red[4][3][256];
    *(f32x4*)&red[w][0][l * 4] = ew;
    *(f32x4*)&red[w][1][l * 4] = ss;
    *(f32x4*)&red[w][2][l * 4] = mxv;
    __syncthreads();
    float ewt = red[0][0][tid] + red[1][0][tid] + red[2][0][tid] + red[3][0][tid];
    float sst = red[0][1][tid] + red[1][1][tid] + red[2][1][tid] + red[3][1][tid];
    float mxt = fmaxf(fmaxf(red[0][2][tid], red[1][2][tid]),
                      fmaxf(red[2][2][tid], red[3][2][tid]));

    size_t ob = (size_t)g * (3 * D_IN);
    out[ob + tid] = ewt * invZ;
    out[ob + D_IN + tid] = (end > start) ? mxt : 0.f;
    out[ob + 2 * D_IN + tid] = sst / (float)max(cnt, 1);
}

// ---------------------------------------------------------------------------
extern "C" void kernel_launch(void* const* d_in, const int* in_sizes, int n_in,
                              void* d_out, int out_size, void* d_ws, size_t ws_size,
                              hipStream_t stream) {
    const float* x = (const float*)d_in[0];
    const float* W1 = (const float*)d_in[1];
    const float* b1 = (const float*)d_in[2];
    const float* W2 = (const float*)d_in[3];
    const float* b2 = (const float*)d_in[4];
    const int* batch = (const int*)d_in[5];
    int N = in_sizes[0] / D_IN;
    float* out = (float*)d_out;
    int NB = (N + CHUNK - 1) / CHUNK;
    int NBLK = (NB + KCH - 1) / KCH;

    char* ws = (char*)d_ws;
    size_t off = 0;
    ushort* w1p = (ushort*)(ws + off);
    off += 8 * 8 * 64 * 8 * sizeof(ushort);  // 64 KB
    off = (off + 255) & ~(size_t)255;
    float* recs = (float*)(ws + off);
    off += (size_t)NB * MAXSEG * 4 * REC_F * sizeof(float);  // ~384 MB
    off = (off + 255) & ~(size_t)255;
    int2* hdr = (int2*)(ws + off);
    off += (size_t)NB * MAXSEG * sizeof(int2);
    off = (off + 255) & ~(size_t)255;
    float* zpart = (float*)(ws + off);
    off += (size_t)NBLK * sizeof(float);
    off = (off + 255) & ~(size_t)255;
    float* MZ = (float*)(ws + off);
    off += 256;

    pack_w1<<<16, 256, 0, stream>>>(W1, w1p);
    fused_kernel<<<NBLK, 256, 0, stream>>>(x, w1p, b1, W2, b2, batch,
                                           recs, hdr, zpart, N, NB);
    zreduce_kernel<<<1, 256, 0, stream>>>(zpart, NBLK, MZ);
    combine_kernel<<<NUM_GRAPHS, 256, 0, stream>>>(recs, hdr, MZ, batch, N, out);
}

// Round 10
// 227.100 us; speedup vs baseline: 1.0781x; 1.0781x over previous
//
#include <hip/hip_runtime.h>
#include <cmath>

#define D_IN 256
#define H_DIM 128
#define NUM_GRAPHS 1024
#define REC_F 768  // floats per graph record: ewsum[256], ssum[256], mx[256]

typedef __attribute__((ext_vector_type(8))) __bf16 bf16x8;
typedef __attribute__((ext_vector_type(4))) float f32x4;
typedef __attribute__((ext_vector_type(4))) unsigned short ushort4v;

__device__ inline float b2f(unsigned short u) {
    unsigned int v = ((unsigned int)u) << 16;
    return __builtin_bit_cast(float, v);
}

// lgkm-only barrier: does NOT drain vmcnt -> prefetch loads stay in flight.
__device__ inline void bar_lds() {
    asm volatile("s_waitcnt lgkmcnt(0)" ::: "memory");
    __builtin_amdgcn_s_barrier();
    asm volatile("" ::: "memory");
}

__device__ inline int lower_bound_i(const int* __restrict__ arr, int n, int val) {
    int lo = 0, hi = n;
    while (lo < hi) {
        int mid = (lo + hi) >> 1;
        if (arr[mid] < val) lo = mid + 1; else hi = mid;
    }
    return lo;
}

// ---------------------------------------------------------------------------
// prep: blocks 0-15 pack W1 into MFMA B-frag order; blocks 16-20 compute
// per-graph bounds via binary search on sorted batch.
// B-frag: lane l holds B[k][n], n = nt*16+(l&15), k = ks*32+(l>>4)*8+i.
// packed[((nt*8+ks)*64 + l)*8 + i]
// ---------------------------------------------------------------------------
__global__ __launch_bounds__(256) void prep_kernel(
    const float* __restrict__ W1, const int* __restrict__ batch, int N,
    ushort* __restrict__ packed, int* __restrict__ bounds) {
    int b = blockIdx.x;
    if (b < 16) {
        int tid = b * 256 + threadIdx.x;
        int nt = tid >> 9;
        int ks = (tid >> 6) & 7;
        int l = tid & 63;
        int col = nt * 16 + (l & 15);
        int kbase = ks * 32 + ((l >> 4) & 3) * 8;
#pragma unroll
        for (int i = 0; i < 8; ++i) {
            float v = W1[(size_t)(kbase + i) * H_DIM + col];
            __bf16 h = (__bf16)v;
            packed[(size_t)tid * 8 + i] = __builtin_bit_cast(unsigned short, h);
        }
    } else {
        int i = (b - 16) * 256 + threadIdx.x;
        if (i <= NUM_GRAPHS) bounds[i] = lower_bound_i(batch, N, i);
    }
}

// ---------------------------------------------------------------------------
// Fused: ONE BLOCK PER GRAPH (512 threads = 8 waves). Wave w owns H-cols
// [w*16,+16) with its 8KB W1 slice in registers. Loop over 64-row windows of
// the graph: stage bf16->LDS (swizzled), MFMA scores, exp, pool (accumulate
// in regs across windows). Next window's x prefetched during compute; lgkm-
// only barriers (2/window) keep loads in flight. One 3KB record per graph.
// ---------------------------------------------------------------------------
__global__ __launch_bounds__(512) void fused_kernel(
    const float* __restrict__ x, const ushort* __restrict__ w1p,
    const float* __restrict__ b1, const float* __restrict__ W2,
    const float* __restrict__ b2, const int* __restrict__ bounds,
    float* __restrict__ recs, float* __restrict__ zpart, int N) {
    int tid = threadIdx.x;
    int l = tid & 63;
    int w = tid >> 6;
    int r16 = l & 15;
    int kg = l >> 4;
    int g = blockIdx.x;
    int start = bounds[g];
    int end = bounds[g + 1];
    int T = (end - start + 63) >> 6;

    __shared__ ushort sx[64 * D_IN];  // 32 KB bf16 window, XOR-swizzled
    __shared__ float pscore[8][64];   // [wave][row] partial scores

    // ---- per-block: W1 slice (nt=w) + epilogue constants -> registers ----
    bf16x8 breg[8];
#pragma unroll
    for (int ks = 0; ks < 8; ++ks)
        breg[ks] = *(const bf16x8*)(w1p + ((size_t)(w * 8 + ks) * 64 + l) * 8);
    float w2v = W2[w * 16 + r16];
    float b1v = b1[w * 16 + r16];
    float bb = b2[0];

    int srow = tid >> 3;  // staging row (== one of this wave's pool rows)
    int sseg = tid & 7;   // 32-float granule within the row

    // per-graph accumulators
    f32x4 asum = {0.f, 0.f, 0.f, 0.f};
    f32x4 ssum = {0.f, 0.f, 0.f, 0.f};
    f32x4 mx = {-INFINITY, -INFINITY, -INFINITY, -INFINITY};
    float zacc = 0.f;

    // ---- prefetch window 0 ----
    f32x4 xv[8];
    if (T > 0) {
        long long grow = (long long)start + srow;
        if (grow >= N) grow = N - 1;
        const float* xr = x + grow * D_IN + sseg * 32;
#pragma unroll
        for (int k = 0; k < 4; ++k) {
            xv[2 * k] = *(const f32x4*)(xr + k * 8);
            xv[2 * k + 1] = *(const f32x4*)(xr + k * 8 + 4);
        }
    }

    for (int t = 0; t < T; ++t) {
        int base = start + t * 64;

        // ---- STAGE: cvt xv -> sx (compiler waits vmcnt on xv use) ----
        {
            unsigned rowswz = (unsigned)(srow & 7) << 4;
#pragma unroll
            for (int k = 0; k < 4; ++k) {
                bf16x8 pk;
#pragma unroll
                for (int i = 0; i < 4; ++i) {
                    pk[i] = (__bf16)xv[2 * k][i];
                    pk[i + 4] = (__bf16)xv[2 * k + 1][i];
                }
                unsigned addr = ((unsigned)(srow * 512 + sseg * 64 + k * 16)) ^ rowswz;
                *(bf16x8*)((char*)sx + addr) = pk;
            }
        }

        // ---- issue prefetch for window t+1 (xv regs now dead) ----
        if (t + 1 < T) {
            long long grow = (long long)base + 64 + srow;
            if (grow >= N) grow = N - 1;
            const float* xr = x + grow * D_IN + sseg * 32;
#pragma unroll
            for (int k = 0; k < 4; ++k) {
                xv[2 * k] = *(const f32x4*)(xr + k * 8);
                xv[2 * k + 1] = *(const f32x4*)(xr + k * 8 + 4);
            }
        }

        bar_lds();  // A: sx ready (prefetch stays in flight)

        // ---- MFMA: 4 row-tiles x this wave's single n-tile ----
        f32x4 acc[4] = {};
#pragma unroll
        for (int ks = 0; ks < 8; ++ks) {
#pragma unroll
            for (int mt = 0; mt < 4; ++mt) {
                int row = mt * 16 + r16;
                unsigned addr = ((unsigned)(row * 512 + ks * 64 + kg * 16)) ^
                                ((unsigned)(row & 7) << 4);
                bf16x8 af = *(const bf16x8*)((const char*)sx + addr);
                acc[mt] = __builtin_amdgcn_mfma_f32_16x16x32_bf16(af, breg[ks], acc[mt], 0, 0, 0);
            }
        }
        // partial-score epilogue over this wave's 16 cols
#pragma unroll
        for (int mt = 0; mt < 4; ++mt) {
#pragma unroll
            for (int reg = 0; reg < 4; ++reg) {
                float p = fmaxf(acc[mt][reg] + b1v, 0.f) * w2v;
                p += __shfl_xor(p, 1, 64);
                p += __shfl_xor(p, 2, 64);
                p += __shfl_xor(p, 4, 64);
                p += __shfl_xor(p, 8, 64);
                if (r16 == 0) pscore[w][mt * 16 + kg * 4 + reg] = p;
            }
        }

        bar_lds();  // B: pscore complete

        // ---- e per lane (redundant in all waves) ----
        float s = bb;
#pragma unroll
        for (int wv = 0; wv < 8; ++wv) s += pscore[wv][l];
        float e_l = (base + l < end) ? __expf(s) : 0.f;
        if (w == 0) zacc += e_l;

        // ---- POOL: wave w pools rows [w*8,+8) == its staged rows ----
#pragma unroll
        for (int j = 0; j < 8; ++j) {
            int row = w * 8 + j;
            float wj = __shfl(e_l, row, 64);
            bool in = (base + row < end);
            unsigned addr = ((unsigned)(row * 512 + l * 8)) ^
                            ((unsigned)(row & 7) << 4);
            ushort4v hv = *(const ushort4v*)((const char*)sx + addr);
            float wje = in ? wj : 0.f;
#pragma unroll
            for (int c = 0; c < 4; ++c) {
                float v = b2f(hv[c]);
                asum[c] += v * wje;
                ssum[c] += in ? v : 0.f;
                mx[c] = fmaxf(mx[c], in ? v : -INFINITY);
            }
        }
        // next iteration's stage writes only this wave's own rows -> no barrier
    }

    // ---- final cross-wave reduce (overlay red on sx) ----
    bar_lds();  // all pools done before overlay
    float* red = (float*)sx;  // [8][3][256] = 24 KB
    *(f32x4*)&red[(w * 3 + 0) * 256 + l * 4] = asum;
    *(f32x4*)&red[(w * 3 + 1) * 256 + l * 4] = ssum;
    *(f32x4*)&red[(w * 3 + 2) * 256 + l * 4] = mx;
    bar_lds();
    if (tid < 256) {
        float a = 0.f, sm = 0.f, m = -INFINITY;
#pragma unroll
        for (int wv = 0; wv < 8; ++wv) {
            a += red[(wv * 3 + 0) * 256 + tid];
            sm += red[(wv * 3 + 1) * 256 + tid];
            m = fmaxf(m, red[(wv * 3 + 2) * 256 + tid]);
        }
        float* rb = recs + (size_t)g * REC_F;
        rb[tid] = a;
        rb[256 + tid] = sm;
        rb[512 + tid] = m;
    }
    if (w == 0) {
        zacc += __shfl_xor(zacc, 1, 64);
        zacc += __shfl_xor(zacc, 2, 64);
        zacc += __shfl_xor(zacc, 4, 64);
        zacc += __shfl_xor(zacc, 8, 64);
        zacc += __shfl_xor(zacc, 16, 64);
        zacc += __shfl_xor(zacc, 32, 64);
        if (l == 0) zpart[g] = zacc;
    }
}

// ---------------------------------------------------------------------------
__global__ __launch_bounds__(256) void zreduce_kernel(
    const float* __restrict__ zpart, int n, float* __restrict__ MZ) {
    int tid = threadIdx.x;
    float z = 0.f;
    for (int i = tid; i < n; i += 256) z += zpart[i];
    __shared__ float sz[256];
    sz[tid] = z;
    __syncthreads();
    for (int off = 128; off > 0; off >>= 1) {
        if (tid < off) sz[tid] += sz[tid + off];
        __syncthreads();
    }
    if (tid == 0) MZ[0] = 1.f / sz[0];
}

// ---------------------------------------------------------------------------
// scale: one block per graph; normalize and write the 768 outputs.
// ---------------------------------------------------------------------------
__global__ __launch_bounds__(256) void scale_kernel(
    const float* __restrict__ recs, const float* __restrict__ MZ,
    const int* __restrict__ bounds, float* __restrict__ out) {
    int g = blockIdx.x;
    int tid = threadIdx.x;
    float invZ = MZ[0];
    int cnt = bounds[g + 1] - bounds[g];
    const float* rb = recs + (size_t)g * REC_F;
    size_t ob = (size_t)g * (3 * D_IN);
    out[ob + tid] = rb[tid] * invZ;
    out[ob + D_IN + tid] = (cnt > 0) ? rb[512 + tid] : 0.f;
    out[ob + 2 * D_IN + tid] = rb[256 + tid] / (float)max(cnt, 1);
}

// ---------------------------------------------------------------------------
extern "C" void kernel_launch(void* const* d_in, const int* in_sizes, int n_in,
                              void* d_out, int out_size, void* d_ws, size_t ws_size,
                              hipStream_t stream) {
    const float* x = (const float*)d_in[0];
    const float* W1 = (const float*)d_in[1];
    const float* b1 = (const float*)d_in[2];
    const float* W2 = (const float*)d_in[3];
    const float* b2 = (const float*)d_in[4];
    const int* batch = (const int*)d_in[5];
    int N = in_sizes[0] / D_IN;
    float* out = (float*)d_out;

    char* ws = (char*)d_ws;
    size_t off = 0;
    ushort* w1p = (ushort*)(ws + off);
    off += 8 * 8 * 64 * 8 * sizeof(ushort);  // 64 KB
    off = (off + 255) & ~(size_t)255;
    int* bounds = (int*)(ws + off);
    off += (NUM_GRAPHS + 1) * sizeof(int);
    off = (off + 255) & ~(size_t)255;
    float* recs = (float*)(ws + off);
    off += (size_t)NUM_GRAPHS * REC_F * sizeof(float);  // 3 MB
    off = (off + 255) & ~(size_t)255;
    float* zpart = (float*)(ws + off);
    off += NUM_GRAPHS * sizeof(float);
    off = (off + 255) & ~(size_t)255;
    float* MZ = (float*)(ws + off);
    off += 256;

    prep_kernel<<<21, 256, 0, stream>>>(W1, batch, N, w1p, bounds);
    fused_kernel<<<NUM_GRAPHS, 512, 0, stream>>>(x, w1p, b1, W2, b2, bounds,
                                                 recs, zpart, N);
    zreduce_kernel<<<1, 256, 0, stream>>>(zpart, NUM_GRAPHS, MZ);
    scale_kernel<<<NUM_GRAPHS, 256, 0, stream>>>(recs, MZ, bounds, out);
}

// Round 11
// 178.194 us; speedup vs baseline: 1.3740x; 1.2745x over previous
//
#include <hip/hip_runtime.h>
#include <cmath>

#define D_IN 256
#define H_DIM 128
#define NUM_GRAPHS 1024
#define CHUNK 64
#define MAXSEG 4
#define REC_F 768  // floats per record: ewsum[256], ssum[256], mx[256]

typedef __attribute__((ext_vector_type(8))) __bf16 bf16x8;
typedef __attribute__((ext_vector_type(4))) float f32x4;
typedef __attribute__((ext_vector_type(4))) unsigned short ushort4v;

__device__ inline float b2f(unsigned short u) {
    unsigned int v = ((unsigned int)u) << 16;
    return __builtin_bit_cast(float, v);
}

__device__ inline int lower_bound_i(const int* __restrict__ arr, int n, int val) {
    int lo = 0, hi = n;
    while (lo < hi) {
        int mid = (lo + hi) >> 1;
        if (arr[mid] < val) lo = mid + 1; else hi = mid;
    }
    return lo;
}

// ---------------------------------------------------------------------------
// prep: blocks 0-15 pack W1 to MFMA B-frag order; blocks 16-20: per-graph
// bounds via binary search; blocks 21+: cfirst[b] = batch[b*64].
// B-frag: lane l holds B[k][n], n = nt*16+(l&15), k = ks*32+(l>>4)*8+i.
// ---------------------------------------------------------------------------
__global__ __launch_bounds__(256) void prep_kernel(
    const float* __restrict__ W1, const int* __restrict__ batch, int N, int NB,
    ushort* __restrict__ packed, int* __restrict__ bounds,
    int* __restrict__ cfirst) {
    int b = blockIdx.x;
    if (b < 16) {
        int tid = b * 256 + threadIdx.x;
        int nt = tid >> 9;
        int ks = (tid >> 6) & 7;
        int l = tid & 63;
        int col = nt * 16 + (l & 15);
        int kbase = ks * 32 + ((l >> 4) & 3) * 8;
#pragma unroll
        for (int i = 0; i < 8; ++i) {
            float v = W1[(size_t)(kbase + i) * H_DIM + col];
            __bf16 h = (__bf16)v;
            packed[(size_t)tid * 8 + i] = __builtin_bit_cast(unsigned short, h);
        }
    } else if (b < 21) {
        int i = (b - 16) * 256 + threadIdx.x;
        if (i <= NUM_GRAPHS) bounds[i] = lower_bound_i(batch, N, i);
    } else {
        int i = (b - 21) * 256 + threadIdx.x;
        if (i < NB) cfirst[i] = batch[(long long)i * CHUNK];
    }
}

// ---------------------------------------------------------------------------
// Fused kernel (R6 structure): one 64-row chunk per block, 256 threads.
// Score: nt-split, wave w owns H-cols [w*32,+32), W1 slice in registers.
// Pool: COLUMN-split, wave w owns x-cols [w*64,+64) over all 64 rows ->
// waves write disjoint quarters of ONE record per (chunk,seg).
// ---------------------------------------------------------------------------
__global__ __launch_bounds__(256) void fused_kernel(
    const float* __restrict__ x, const ushort* __restrict__ w1p,
    const float* __restrict__ b1, const float* __restrict__ W2,
    const float* __restrict__ b2, const int* __restrict__ batch,
    float* __restrict__ recs, float* __restrict__ zpart, int N) {
    int tid = threadIdx.x;
    int l = tid & 63;
    int w = tid >> 6;
    int r16 = l & 15;
    int kg = l >> 4;
    int blk = blockIdx.x;
    long long base = (long long)blk * CHUNK;
    int chunkN = (int)min((long long)CHUNK, (long long)N - base);

    __shared__ ushort sx[CHUNK * D_IN];     // 32 KB bf16 tile, XOR-swizzled
    __shared__ float pscore[4][CHUNK];      // [wave][row]
    __shared__ int seglist[MAXSEG + 1];
    __shared__ int snseg;

    // ---- wave0: batch values (early) ----
    int bval = -1;
    if (w == 0) {
        long long bi = base + l;
        bval = (bi < N) ? batch[bi] : -1;
    }

    // ---- per-wave W1 slice -> registers ----
    bf16x8 breg0[8], breg1[8];
#pragma unroll
    for (int ks = 0; ks < 8; ++ks) {
        breg0[ks] = *(const bf16x8*)(w1p + ((size_t)((w * 2) * 8 + ks) * 64 + l) * 8);
        breg1[ks] = *(const bf16x8*)(w1p + ((size_t)((w * 2 + 1) * 8 + ks) * 64 + l) * 8);
    }

    // ---- STAGE: thread t -> row t>>2, granules (t&3)+4j; hoisted loads ----
    {
        int row = tid >> 2;
        long long grow = base + row;
        if (grow >= N) grow = N - 1;
        const float* xr = x + grow * D_IN;
        int gb = tid & 3;
        f32x4 xv[16];
#pragma unroll
        for (int j = 0; j < 8; ++j) {
            int g = gb + 4 * j;
            xv[2 * j] = *(const f32x4*)(xr + g * 8);
            xv[2 * j + 1] = *(const f32x4*)(xr + g * 8 + 4);
        }
        unsigned rowswz = (unsigned)(row & 7) << 4;
#pragma unroll
        for (int j = 0; j < 8; ++j) {
            int g = gb + 4 * j;
            bf16x8 pk;
#pragma unroll
            for (int i = 0; i < 4; ++i) {
                pk[i] = (__bf16)xv[2 * j][i];
                pk[i + 4] = (__bf16)xv[2 * j + 1][i];
            }
            unsigned addr = ((unsigned)(row * 512 + g * 16)) ^ rowswz;
            *(bf16x8*)((char*)sx + addr) = pk;
        }
    }

    // epilogue constants for this wave's 32 H-cols
    float w2v[2], b1v[2];
#pragma unroll
    for (int q = 0; q < 2; ++q) {
        int c = (w * 2 + q) * 16 + r16;
        w2v[q] = W2[c];
        b1v[q] = b1[c];
    }
    float bb = b2[0];

    // ---- wave0: segment scan (no LDS needed) ----
    if (w == 0) {
        int prev = __shfl_up(bval, 1, 64);
        bool flag = (l < chunkN) && (l == 0 || bval != prev);
        unsigned long long m = __ballot(flag);
        if (l == 0) {
            int ns = 0;
            while (m && ns < MAXSEG) {
                int b = __ffsll(m) - 1;
                seglist[ns] = b;
                ns++;
                m &= m - 1;
            }
            snseg = ns;
            seglist[ns] = chunkN;
        }
    }
    __syncthreads();  // barrier A: sx + seglist ready

    // ---- MFMA: acc[mt][q] over 4 row-tiles x this wave's 2 n-tiles ----
    f32x4 acc[4][2] = {};
#pragma unroll
    for (int ks = 0; ks < 8; ++ks) {
#pragma unroll
        for (int mt = 0; mt < 4; ++mt) {
            int row = mt * 16 + r16;
            unsigned addr = ((unsigned)(row * 512 + ks * 64 + kg * 16)) ^
                            ((unsigned)(row & 7) << 4);
            bf16x8 af = *(const bf16x8*)((const char*)sx + addr);
            acc[mt][0] = __builtin_amdgcn_mfma_f32_16x16x32_bf16(af, breg0[ks], acc[mt][0], 0, 0, 0);
            acc[mt][1] = __builtin_amdgcn_mfma_f32_16x16x32_bf16(af, breg1[ks], acc[mt][1], 0, 0, 0);
        }
    }
    // partial-score epilogue over this wave's 32 cols
#pragma unroll
    for (int mt = 0; mt < 4; ++mt) {
#pragma unroll
        for (int reg = 0; reg < 4; ++reg) {
            float p = fmaxf(acc[mt][0][reg] + b1v[0], 0.f) * w2v[0] +
                      fmaxf(acc[mt][1][reg] + b1v[1], 0.f) * w2v[1];
            p += __shfl_xor(p, 1, 64);
            p += __shfl_xor(p, 2, 64);
            p += __shfl_xor(p, 4, 64);
            p += __shfl_xor(p, 8, 64);
            if (r16 == 0) pscore[w][mt * 16 + kg * 4 + reg] = p;
        }
    }
    __syncthreads();  // barrier B: pscore complete

    // ---- e per lane (lane l = row l) ----
    float s = pscore[0][l] + pscore[1][l] + pscore[2][l] + pscore[3][l] + bb;
    float e_l = (l < chunkN) ? __expf(s) : 0.f;

    if (w == 0) {
        float z = e_l;
        z += __shfl_xor(z, 1, 64);
        z += __shfl_xor(z, 2, 64);
        z += __shfl_xor(z, 4, 64);
        z += __shfl_xor(z, 8, 64);
        z += __shfl_xor(z, 16, 64);
        z += __shfl_xor(z, 32, 64);
        if (l == 0) zpart[blk] = z;
    }

    int nseg = snseg;

    // ---- POOL (column-split): wave w cols [w*64,+64); lane: cg=l&15 col
    // group, rg=l>>4 row group (rows rg+4j). Intra-wave shfl reduce ->
    // disjoint record quarters; ONE record per (blk,seg).
    int cg = l & 15;
    int rg = l >> 4;
    unsigned cbyte = (unsigned)(w * 128 + cg * 8);

    for (int sg = 0; sg < nseg; ++sg) {
        int sStart = seglist[sg];
        int sEnd = seglist[sg + 1];
        f32x4 asum = {0.f, 0.f, 0.f, 0.f};
        f32x4 ssum = {0.f, 0.f, 0.f, 0.f};
        f32x4 mx = {-INFINITY, -INFINITY, -INFINITY, -INFINITY};
#pragma unroll
        for (int j = 0; j < 16; ++j) {
            int row = rg + 4 * j;
            float wj = __shfl(e_l, row, 64);
            bool in = (row >= sStart) && (row < sEnd);
            unsigned addr = ((unsigned)(row * 512) + cbyte) ^
                            ((unsigned)(row & 7) << 4);
            ushort4v hv = *(const ushort4v*)((const char*)sx + addr);
            float wje = in ? wj : 0.f;
#pragma unroll
            for (int c = 0; c < 4; ++c) {
                float v = b2f(hv[c]);
                asum[c] += v * wje;
                ssum[c] += in ? v : 0.f;
                mx[c] = fmaxf(mx[c], in ? v : -INFINITY);
            }
        }
        // reduce across the 4 row-groups
#pragma unroll
        for (int c = 0; c < 4; ++c) {
            asum[c] += __shfl_xor(asum[c], 16, 64);
            asum[c] += __shfl_xor(asum[c], 32, 64);
            ssum[c] += __shfl_xor(ssum[c], 16, 64);
            ssum[c] += __shfl_xor(ssum[c], 32, 64);
            mx[c] = fmaxf(mx[c], __shfl_xor(mx[c], 16, 64));
            mx[c] = fmaxf(mx[c], __shfl_xor(mx[c], 32, 64));
        }
        if (rg == 0) {
            float* rb = recs + (size_t)(blk * MAXSEG + sg) * REC_F;
            int co = w * 64 + cg * 4;
            *(f32x4*)(rb + co) = asum;
            *(f32x4*)(rb + 256 + co) = ssum;
            *(f32x4*)(rb + 512 + co) = mx;
        }
    }
}

// ---------------------------------------------------------------------------
__global__ __launch_bounds__(256) void zreduce_kernel(
    const float* __restrict__ zpart, int n, float* __restrict__ MZ) {
    int tid = threadIdx.x;
    float z = 0.f;
    for (int i = tid; i < n; i += 256) z += zpart[i];
    __shared__ float sz[256];
    sz[tid] = z;
    __syncthreads();
    for (int off = 128; off > 0; off >>= 1) {
        if (tid < off) sz[tid] += sz[tid + off];
        __syncthreads();
    }
    if (tid == 0) MZ[0] = 1.f / sz[0];
}

// ---------------------------------------------------------------------------
// combine: one block per graph. Direct record indexing via bounds + cfirst
// (seg index of graph g in chunk b = g - cfirst[b]); no search, no hdr scan.
// ---------------------------------------------------------------------------
__global__ __launch_bounds__(256) void combine_kernel(
    const float* __restrict__ recs, const int* __restrict__ bounds,
    const int* __restrict__ cfirst, const float* __restrict__ MZ,
    float* __restrict__ out) {
    int g = blockIdx.x;
    int tid = threadIdx.x;
    float invZ = MZ[0];
    int start = bounds[g];
    int end = bounds[g + 1];
    int cnt = end - start;

    float ew = 0.f, ss = 0.f, mxv = -INFINITY;
    if (cnt > 0) {
        int b0 = start >> 6, b1 = (end - 1) >> 6;
        for (int b = b0; b <= b1; ++b) {
            int sg = g - cfirst[b];
            if (sg >= 0 && sg < MAXSEG) {
                const float* rb = recs + (size_t)(b * MAXSEG + sg) * REC_F;
                ew += rb[tid];
                ss += rb[256 + tid];
                mxv = fmaxf(mxv, rb[512 + tid]);
            }
        }
    }
    size_t ob = (size_t)g * (3 * D_IN);
    out[ob + tid] = ew * invZ;
    out[ob + D_IN + tid] = (cnt > 0) ? mxv : 0.f;
    out[ob + 2 * D_IN + tid] = ss / (float)max(cnt, 1);
}

// ---------------------------------------------------------------------------
extern "C" void kernel_launch(void* const* d_in, const int* in_sizes, int n_in,
                              void* d_out, int out_size, void* d_ws, size_t ws_size,
                              hipStream_t stream) {
    const float* x = (const float*)d_in[0];
    const float* W1 = (const float*)d_in[1];
    const float* b1 = (const float*)d_in[2];
    const float* W2 = (const float*)d_in[3];
    const float* b2 = (const float*)d_in[4];
    const int* batch = (const int*)d_in[5];
    int N = in_sizes[0] / D_IN;
    float* out = (float*)d_out;
    int NB = (N + CHUNK - 1) / CHUNK;

    char* ws = (char*)d_ws;
    size_t off = 0;
    ushort* w1p = (ushort*)(ws + off);
    off += 8 * 8 * 64 * 8 * sizeof(ushort);  // 64 KB
    off = (off + 255) & ~(size_t)255;
    int* bounds = (int*)(ws + off);
    off += (NUM_GRAPHS + 1) * sizeof(int);
    off = (off + 255) & ~(size_t)255;
    int* cfirst = (int*)(ws + off);
    off += (size_t)NB * sizeof(int);
    off = (off + 255) & ~(size_t)255;
    float* recs = (float*)(ws + off);
    off += (size_t)NB * MAXSEG * REC_F * sizeof(float);  // ~96 MB
    off = (off + 255) & ~(size_t)255;
    float* zpart = (float*)(ws + off);
    off += (size_t)NB * sizeof(float);
    off = (off + 255) & ~(size_t)255;
    float* MZ = (float*)(ws + off);
    off += 256;

    int prepBlocks = 21 + (NB + 255) / 256;
    prep_kernel<<<prepBlocks, 256, 0, stream>>>(W1, batch, N, NB, w1p, bounds, cfirst);
    fused_kernel<<<NB, 256, 0, stream>>>(x, w1p, b1, W2, b2, batch,
                                         recs, zpart, N);
    zreduce_kernel<<<1, 256, 0, stream>>>(zpart, NB, MZ);
    combine_kernel<<<NUM_GRAPHS, 256, 0, stream>>>(recs, bounds, cfirst, MZ, out);
}

// Round 12
// 174.817 us; speedup vs baseline: 1.4006x; 1.0193x over previous
//
#include <hip/hip_runtime.h>
#include <cmath>

#define D_IN 256
#define H_DIM 128
#define NUM_GRAPHS 1024
#define CHUNK 32
#define MAXSEG 2
#define REC_F 768  // floats per record: ewsum[256], ssum[256], mx[256]

typedef __attribute__((ext_vector_type(8))) __bf16 bf16x8;
typedef __attribute__((ext_vector_type(4))) float f32x4;

// async global->LDS DMA, 16B per lane: dest = wave-uniform base + lane*16.
__device__ inline void load_lds_16(const void* g, void* l) {
    __builtin_amdgcn_global_load_lds(
        (const __attribute__((address_space(1))) void*)g,
        (__attribute__((address_space(3))) void*)l, 16, 0, 0);
}

__device__ inline int lower_bound_i(const int* __restrict__ arr, int n, int val) {
    int lo = 0, hi = n;
    while (lo < hi) {
        int mid = (lo + hi) >> 1;
        if (arr[mid] < val) lo = mid + 1; else hi = mid;
    }
    return lo;
}

// ---------------------------------------------------------------------------
// prep: blocks 0-15 pack W1 to MFMA B-frag order; blocks 16-20: per-graph
// bounds via binary search on sorted batch.
// B-frag: lane l holds B[k][n], n = nt*16+(l&15), k = ks*32+(l>>4)*8+i.
// ---------------------------------------------------------------------------
__global__ __launch_bounds__(256) void prep_kernel(
    const float* __restrict__ W1, const int* __restrict__ batch, int N,
    ushort* __restrict__ packed, int* __restrict__ bounds) {
    int b = blockIdx.x;
    if (b < 16) {
        int tid = b * 256 + threadIdx.x;
        int nt = tid >> 9;
        int ks = (tid >> 6) & 7;
        int l = tid & 63;
        int col = nt * 16 + (l & 15);
        int kbase = ks * 32 + ((l >> 4) & 3) * 8;
#pragma unroll
        for (int i = 0; i < 8; ++i) {
            float v = W1[(size_t)(kbase + i) * H_DIM + col];
            __bf16 h = (__bf16)v;
            packed[(size_t)tid * 8 + i] = __builtin_bit_cast(unsigned short, h);
        }
    } else {
        int i = (b - 16) * 256 + threadIdx.x;
        if (i <= NUM_GRAPHS) bounds[i] = lower_bound_i(batch, N, i);
    }
}

// ---------------------------------------------------------------------------
// Fused kernel: one 32-row chunk per block (15626 blocks), 256 threads.
// x staged via global_load_lds DMA (f32, linear LDS, source-swizzled so reads
// are conflict-free). Score: nt-split, wave w owns H-cols [w*32,+32), W1 in
// regs. Pool: column-split (wave w owns x-cols [w*64,+64)), f32 from LDS,
// disjoint record quarters, ONE record per (chunk,seg).
// ---------------------------------------------------------------------------
__global__ __launch_bounds__(256, 4) void fused_kernel(
    const float* __restrict__ x, const ushort* __restrict__ w1p,
    const float* __restrict__ b1, const float* __restrict__ W2,
    const float* __restrict__ b2, const int* __restrict__ batch,
    float* __restrict__ recs, float* __restrict__ zpart, int N) {
    int tid = threadIdx.x;
    int l = tid & 63;
    int w = tid >> 6;
    int r16 = l & 15;
    int kg = l >> 4;
    int blk = blockIdx.x;
    long long base = (long long)blk * CHUNK;
    int chunkN = (int)min((long long)CHUNK, (long long)N - base);

    __shared__ float sxf[CHUNK * D_IN];  // 32 KB f32 tile (source-swizzled)
    __shared__ float pscore[4][CHUNK];   // [wave][row]
    __shared__ int seglist[MAXSEG + 1];
    __shared__ int snseg;

    // ---- 1. DMA x rows -> LDS. Per (k,w): one row; dest = row*1024 + l*16;
    //      source granule within row: (l*16) ^ ((row&7)<<4).
#pragma unroll
    for (int k = 0; k < 8; ++k) {
        int row = k * 4 + w;
        long long grow = base + row;
        if (grow >= N) grow = N - 1;
        unsigned srcb = ((unsigned)(l * 16)) ^ ((unsigned)(row & 7) << 4);
        const float* src = x + grow * D_IN + (srcb >> 2);
        char* dst = (char*)sxf + (unsigned)(row * 1024 + l * 16);
        load_lds_16(src, dst);
    }

    // ---- 2. per-wave W1 slice -> registers (no staging pressure now) ----
    bf16x8 breg0[8], breg1[8];
#pragma unroll
    for (int ks = 0; ks < 8; ++ks) {
        breg0[ks] = *(const bf16x8*)(w1p + ((size_t)((w * 2) * 8 + ks) * 64 + l) * 8);
        breg1[ks] = *(const bf16x8*)(w1p + ((size_t)((w * 2 + 1) * 8 + ks) * 64 + l) * 8);
    }

    // ---- 3. wave0: batch + segment scan ----
    if (w == 0) {
        int bval = -1;
        if (l < chunkN) bval = batch[base + l];
        int prev = __shfl_up(bval, 1, 64);
        bool flag = (l < chunkN) && (l == 0 || bval != prev);
        unsigned long long m = __ballot(flag);
        if (l == 0) {
            int ns = 0;
            while (m && ns < MAXSEG) {
                seglist[ns] = __ffsll(m) - 1;
                ns++;
                m &= m - 1;
            }
            snseg = ns;
            seglist[ns] = chunkN;
        }
    }

    // ---- 4. epilogue constants ----
    float w2v[2], b1v[2];
#pragma unroll
    for (int q = 0; q < 2; ++q) {
        int c = (w * 2 + q) * 16 + r16;
        w2v[q] = W2[c];
        b1v[q] = b1[c];
    }
    float bb = b2[0];

    __syncthreads();  // barrier A: vmcnt(0) drains DMA; seglist ready

    // ---- 5. MFMA: read f32 A-frags from LDS, cvt, 2 n-tiles ----
    f32x4 acc[2][2] = {};
#pragma unroll
    for (int ks = 0; ks < 8; ++ks) {
#pragma unroll
        for (int mt = 0; mt < 2; ++mt) {
            int row = mt * 16 + r16;
            unsigned swz = (unsigned)(row & 7) << 4;
            unsigned cb = (unsigned)(ks * 128 + kg * 32);
            f32x4 u0 = *(const f32x4*)((const char*)sxf + row * 1024 + (cb ^ swz));
            f32x4 u1 = *(const f32x4*)((const char*)sxf + row * 1024 + ((cb + 16) ^ swz));
            bf16x8 af;
#pragma unroll
            for (int i = 0; i < 4; ++i) {
                af[i] = (__bf16)u0[i];
                af[i + 4] = (__bf16)u1[i];
            }
            acc[mt][0] = __builtin_amdgcn_mfma_f32_16x16x32_bf16(af, breg0[ks], acc[mt][0], 0, 0, 0);
            acc[mt][1] = __builtin_amdgcn_mfma_f32_16x16x32_bf16(af, breg1[ks], acc[mt][1], 0, 0, 0);
        }
    }
    // partial-score epilogue over this wave's 32 H-cols
#pragma unroll
    for (int mt = 0; mt < 2; ++mt) {
#pragma unroll
        for (int reg = 0; reg < 4; ++reg) {
            float p = fmaxf(acc[mt][0][reg] + b1v[0], 0.f) * w2v[0] +
                      fmaxf(acc[mt][1][reg] + b1v[1], 0.f) * w2v[1];
            p += __shfl_xor(p, 1, 64);
            p += __shfl_xor(p, 2, 64);
            p += __shfl_xor(p, 4, 64);
            p += __shfl_xor(p, 8, 64);
            if (r16 == 0) pscore[w][mt * 16 + kg * 4 + reg] = p;
        }
    }
    __syncthreads();  // barrier B: pscore complete

    // ---- 6. e per lane (rows are lanes 0..31) ----
    float e_l = 0.f;
    if (l < CHUNK) {
        float s = pscore[0][l] + pscore[1][l] + pscore[2][l] + pscore[3][l] + bb;
        e_l = (l < chunkN) ? __expf(s) : 0.f;
    }
    if (w == 0) {
        float z = e_l;
        z += __shfl_xor(z, 1, 64);
        z += __shfl_xor(z, 2, 64);
        z += __shfl_xor(z, 4, 64);
        z += __shfl_xor(z, 8, 64);
        z += __shfl_xor(z, 16, 64);
        z += __shfl_xor(z, 32, 64);
        if (l == 0) zpart[blk] = z;
    }

    int nseg = snseg;

    // ---- 7. POOL (column-split, f32): wave w cols [w*64,+64);
    //      lane: cg=l&15 -> 4 cols, rg=l>>4 -> rows rg+4j.
    int cg = l & 15;
    int rg = l >> 4;
    unsigned cbyte = (unsigned)(w * 256 + cg * 16);

    for (int sg = 0; sg < nseg; ++sg) {
        int sStart = seglist[sg];
        int sEnd = seglist[sg + 1];
        f32x4 asum = {0.f, 0.f, 0.f, 0.f};
        f32x4 ssum = {0.f, 0.f, 0.f, 0.f};
        f32x4 mx = {-INFINITY, -INFINITY, -INFINITY, -INFINITY};
#pragma unroll
        for (int j = 0; j < 8; ++j) {
            int row = rg + 4 * j;
            float wj = __shfl(e_l, row, 64);
            bool in = (row >= sStart) && (row < sEnd);
            unsigned addr = (unsigned)(row * 1024) +
                            (cbyte ^ ((unsigned)(row & 7) << 4));
            f32x4 v = *(const f32x4*)((const char*)sxf + addr);
            float wje = in ? wj : 0.f;
#pragma unroll
            for (int c = 0; c < 4; ++c) {
                asum[c] += v[c] * wje;
                ssum[c] += in ? v[c] : 0.f;
                mx[c] = fmaxf(mx[c], in ? v[c] : -INFINITY);
            }
        }
        // reduce across the 4 row-groups; lanes rg==0 hold the result
#pragma unroll
        for (int c = 0; c < 4; ++c) {
            asum[c] += __shfl_xor(asum[c], 16, 64);
            asum[c] += __shfl_xor(asum[c], 32, 64);
            ssum[c] += __shfl_xor(ssum[c], 16, 64);
            ssum[c] += __shfl_xor(ssum[c], 32, 64);
            mx[c] = fmaxf(mx[c], __shfl_xor(mx[c], 16, 64));
            mx[c] = fmaxf(mx[c], __shfl_xor(mx[c], 32, 64));
        }
        if (rg == 0) {
            float* rb = recs + (size_t)(blk * MAXSEG + sg) * REC_F;
            int co = w * 64 + cg * 4;
            *(f32x4*)(rb + co) = asum;
            *(f32x4*)(rb + 256 + co) = ssum;
            *(f32x4*)(rb + 512 + co) = mx;
        }
    }
}

// ---------------------------------------------------------------------------
// combine: one block per graph. Z summed in-block (identical order ->
// deterministic). Seg index: 1 in the first chunk iff chunk starts with an
// earlier graph; 0 in all other chunks (<=2 segments per 32-row chunk).
// ---------------------------------------------------------------------------
__global__ __launch_bounds__(256) void combine_kernel(
    const float* __restrict__ recs, const int* __restrict__ bounds,
    const int* __restrict__ batch, const float* __restrict__ zpart, int nzp,
    float* __restrict__ out) {
    int g = blockIdx.x;
    int tid = threadIdx.x;

    __shared__ float szr[256];
    float z = 0.f;
    for (int i = tid; i < nzp; i += 256) z += zpart[i];
    szr[tid] = z;
    __syncthreads();
    for (int off = 128; off > 0; off >>= 1) {
        if (tid < off) szr[tid] += szr[tid + off];
        __syncthreads();
    }
    float invZ = 1.f / szr[0];

    int start = bounds[g];
    int end = bounds[g + 1];
    int cnt = end - start;

    float ew = 0.f, ss = 0.f, mxv = -INFINITY;
    if (cnt > 0) {
        int b0 = start / CHUNK, b1 = (end - 1) / CHUNK;
        int sg0 = (batch[(long long)b0 * CHUNK] == g) ? 0 : 1;
        for (int b = b0; b <= b1; ++b) {
            int sg = (b == b0) ? sg0 : 0;
            const float* rb = recs + (size_t)(b * MAXSEG + sg) * REC_F;
            ew += rb[tid];
            ss += rb[256 + tid];
            mxv = fmaxf(mxv, rb[512 + tid]);
        }
    }
    size_t ob = (size_t)g * (3 * D_IN);
    out[ob + tid] = ew * invZ;
    out[ob + D_IN + tid] = (cnt > 0) ? mxv : 0.f;
    out[ob + 2 * D_IN + tid] = ss / (float)max(cnt, 1);
}

// ---------------------------------------------------------------------------
extern "C" void kernel_launch(void* const* d_in, const int* in_sizes, int n_in,
                              void* d_out, int out_size, void* d_ws, size_t ws_size,
                              hipStream_t stream) {
    const float* x = (const float*)d_in[0];
    const float* W1 = (const float*)d_in[1];
    const float* b1 = (const float*)d_in[2];
    const float* W2 = (const float*)d_in[3];
    const float* b2 = (const float*)d_in[4];
    const int* batch = (const int*)d_in[5];
    int N = in_sizes[0] / D_IN;
    float* out = (float*)d_out;
    int NB = (N + CHUNK - 1) / CHUNK;

    char* ws = (char*)d_ws;
    size_t off = 0;
    ushort* w1p = (ushort*)(ws + off);
    off += 8 * 8 * 64 * 8 * sizeof(ushort);  // 64 KB
    off = (off + 255) & ~(size_t)255;
    int* bounds = (int*)(ws + off);
    off += (NUM_GRAPHS + 1) * sizeof(int);
    off = (off + 255) & ~(size_t)255;
    float* recs = (float*)(ws + off);
    off += (size_t)NB * MAXSEG * REC_F * sizeof(float);  // ~96 MB
    off = (off + 255) & ~(size_t)255;
    float* zpart = (float*)(ws + off);
    off += (size_t)NB * sizeof(float);

    prep_kernel<<<21, 256, 0, stream>>>(W1, batch, N, w1p, bounds);
    fused_kernel<<<NB, 256, 0, stream>>>(x, w1p, b1, W2, b2, batch,
                                         recs, zpart, N);
    combine_kernel<<<NUM_GRAPHS, 256, 0, stream>>>(recs, bounds, batch,
                                                   zpart, NB, out);
}